// Round 7
// baseline (18.782 us; speedup 1.0000x reference)
//
#include <hip/hip_runtime.h>
#include <hip/hip_bf16.h>

// Embedding gather with OOV handling.
// out[r][d] = (idx[r] >= VOCAB) ? oov[d] : emb[idx[r]][d]
// D = 200 floats = 50 float4 per row; rows are 800B => 16B aligned.
//
// R7: revert to the measured-best R2 configuration. Full config matrix:
//   ELEMS=1 NT-store 18.07 | ELEMS=4 NT-store 11.87 (BEST) | ELEMS=8 12.00
//   cached/cached 13.47 | NT-load/cached 15.06 | persistent-800WG 16.70
// Mechanism: latency-bound random gather; performance tracks total in-flight
// gather bytes per CU (waves/CU x ELEMS); 1600 WGs x ELEMS=4 makes the whole
// kernel resident (6400 waves) -> queue-depth-limited. Harness fills 320MB
// between replays, evicting L2+L3 -> mandatory ~47-52MB HBM traffic/replay;
// floor ~9.5-10.5us for random 800B-granule reads. 11.87us is near that.

typedef float f32x4 __attribute__((ext_vector_type(4)));

#define ELEMS 4
#define BLOCK 256

__global__ void embed_gather_kernel(const int* __restrict__ indices,
                                    const f32x4* __restrict__ emb,
                                    const f32x4* __restrict__ oov,
                                    f32x4* __restrict__ out,
                                    int n_vec,      // total float4 elements in output
                                    int vocab) {
    int base = blockIdx.x * (BLOCK * ELEMS) + threadIdx.x;

    int   idx[ELEMS];
    int   off[ELEMS];
    f32x4 val[ELEMS];

    // Phase 1: index loads (cached; L1-hot broadcast across lanes)
    #pragma unroll
    for (int k = 0; k < ELEMS; ++k) {
        int i = base + k * BLOCK;
        int ii = (i < n_vec) ? i : 0;
        int row = ii / 50;          // magic-mul, cheap
        off[k] = ii - row * 50;
        idx[k] = indices[row];
    }

    // Phase 2: gather loads (cached; 4 independent vmem ops in flight)
    #pragma unroll
    for (int k = 0; k < ELEMS; ++k) {
        const f32x4* src = (idx[k] >= vocab)
                         ? (oov + off[k])
                         : (emb + (long long)idx[k] * 50 + off[k]);
        val[k] = *src;
    }

    // Phase 3: nontemporal streaming stores (write-only output; measured
    // best vs cached stores by 1.6us)
    #pragma unroll
    for (int k = 0; k < ELEMS; ++k) {
        int i = base + k * BLOCK;
        if (i < n_vec) {
            __builtin_nontemporal_store(val[k], out + i);
        }
    }
}

extern "C" void kernel_launch(void* const* d_in, const int* in_sizes, int n_in,
                              void* d_out, int out_size, void* d_ws, size_t ws_size,
                              hipStream_t stream) {
    const int*   indices = (const int*)d_in[0];
    const float* emb     = (const float*)d_in[1];
    const float* oov     = (const float*)d_in[2];
    float*       out     = (float*)d_out;

    const int D      = in_sizes[2];            // 200
    const int vocab  = in_sizes[1] / D;        // 100000
    const int n_vec  = out_size / 4;           // float4 count

    const int grid = (n_vec + BLOCK * ELEMS - 1) / (BLOCK * ELEMS);
    embed_gather_kernel<<<grid, BLOCK, 0, stream>>>(
        indices,
        (const f32x4*)emb,
        (const f32x4*)oov,
        (f32x4*)out,
        n_vec, vocab);
}

// Round 8
// 12.022 us; speedup vs baseline: 1.5624x; 1.5624x over previous
//
#include <hip/hip_runtime.h>
#include <hip/hip_bf16.h>

// Embedding gather with OOV handling.
// out[r][d] = (idx[r] >= VOCAB) ? oov[d] : emb[idx[r]][d]
// D = 200 floats = 50 float4 per row; rows are 800B => 16B aligned.
//
// R8: VARIANCE PROBE — identical config to R2/R7 (ELEMS=4, cached gather
// loads, NT stores, 1600 WGs). Same source measured 11.87us (R2) and
// 18.78us (R7): +/-35% run-to-run band for this latency-bound gather
// (fill-kernel calibrations stable at 45-48us -> chip fine; suspect
// physical page mapping of the 80MB table varies per container).
// Config matrix (each n=1, now known noisy):
//   ELEMS=1 18.07 | ELEMS=4 NT 11.87/18.78 | ELEMS=8 12.00
//   cached/cached 13.47 | NT-load 15.06 | persistent-800WG 16.70
// Floor: harness fills 320MB between replays (evicts L2+L3) -> mandatory
// ~47-52MB HBM/replay -> ~8-10us floor. This config is at/near it.

typedef float f32x4 __attribute__((ext_vector_type(4)));

#define ELEMS 4
#define BLOCK 256

__global__ void embed_gather_kernel(const int* __restrict__ indices,
                                    const f32x4* __restrict__ emb,
                                    const f32x4* __restrict__ oov,
                                    f32x4* __restrict__ out,
                                    int n_vec,      // total float4 elements in output
                                    int vocab) {
    int base = blockIdx.x * (BLOCK * ELEMS) + threadIdx.x;

    int   idx[ELEMS];
    int   off[ELEMS];
    f32x4 val[ELEMS];

    // Phase 1: index loads (cached; L1-hot broadcast across lanes)
    #pragma unroll
    for (int k = 0; k < ELEMS; ++k) {
        int i = base + k * BLOCK;
        int ii = (i < n_vec) ? i : 0;
        int row = ii / 50;          // magic-mul, cheap
        off[k] = ii - row * 50;
        idx[k] = indices[row];
    }

    // Phase 2: gather loads (cached; 4 independent vmem ops in flight)
    #pragma unroll
    for (int k = 0; k < ELEMS; ++k) {
        const f32x4* src = (idx[k] >= vocab)
                         ? (oov + off[k])
                         : (emb + (long long)idx[k] * 50 + off[k]);
        val[k] = *src;
    }

    // Phase 3: nontemporal streaming stores (write-only output)
    #pragma unroll
    for (int k = 0; k < ELEMS; ++k) {
        int i = base + k * BLOCK;
        if (i < n_vec) {
            __builtin_nontemporal_store(val[k], out + i);
        }
    }
}

extern "C" void kernel_launch(void* const* d_in, const int* in_sizes, int n_in,
                              void* d_out, int out_size, void* d_ws, size_t ws_size,
                              hipStream_t stream) {
    const int*   indices = (const int*)d_in[0];
    const float* emb     = (const float*)d_in[1];
    const float* oov     = (const float*)d_in[2];
    float*       out     = (float*)d_out;

    const int D      = in_sizes[2];            // 200
    const int vocab  = in_sizes[1] / D;        // 100000
    const int n_vec  = out_size / 4;           // float4 count

    const int grid = (n_vec + BLOCK * ELEMS - 1) / (BLOCK * ELEMS);
    embed_gather_kernel<<<grid, BLOCK, 0, stream>>>(
        indices,
        (const f32x4*)emb,
        (const f32x4*)oov,
        (f32x4*)out,
        n_vec, vocab);
}